// Round 1
// baseline (1416.849 us; speedup 1.0000x reference)
//
#include <hip/hip_runtime.h>

#define HID 128
#define PTS 32      // points per block
#define SA_STR 36   // padded p-stride (multiple of 4 -> 16B-aligned rows)

// tanh(x) = 1 - 2/(exp(2x)+1); v_exp + v_rcp, correct limits at +-inf
__device__ __forceinline__ float fast_tanh(float x) {
    float e = __expf(2.0f * x);
    float r = __builtin_amdgcn_rcpf(e + 1.0f);
    return 1.0f - 2.0f * r;
}

__global__ void zero_out_kernel(float* out) {
    if (threadIdx.x < 2) out[threadIdx.x] = 0.0f;
}

// One block processes PTS=32 points through the whole MLP.
// Channels: 0=value, 1=d/dx, 2=d/dy, 3=laplacian (INTERIOR only).
// Thread tile: tj = tid&31 -> 4 j-columns, tp = tid>>5 -> 4 points.
template <bool INTERIOR>
__global__ __launch_bounds__(256, 1) void pinn_mlp_kernel(
    const float* __restrict__ xy, const float* __restrict__ tgt,
    const float* __restrict__ W0, const float* __restrict__ b0,
    const float* __restrict__ W1, const float* __restrict__ b1,
    const float* __restrict__ W2, const float* __restrict__ b2,
    const float* __restrict__ W3, const float* __restrict__ b3,
    float* __restrict__ out_slot, int n, float scale)
{
    constexpr int NC = INTERIOR ? 4 : 1;
    extern __shared__ float smem[];
    float* sW = smem;                      // HID*HID fp32 (64 KB), current layer W
    float* sA = smem + HID * HID;          // NC * HID * SA_STR, k-major activations
    float* sRed = sA + NC * HID * SA_STR;  // 8 floats

    const int tid = threadIdx.x;
    const int tj = tid & 31;
    const int tp = tid >> 5;
    const int j0 = tj * 4;
    const int p0 = tp * 4;
    const int pbase = blockIdx.x * PTS;

    // ---- stage W1 -> regs early (hide global latency under layer-0 math) ----
    float4 wst[16];
    #pragma unroll
    for (int i = 0; i < 16; ++i)
        wst[i] = ((const float4*)W1)[i * 256 + tid];

    // ---- layer 0: 2 -> 128 ----
    float2 xyv[4];
    #pragma unroll
    for (int pp = 0; pp < 4; ++pp) {
        int p = pbase + p0 + pp;
        float2 v = make_float2(0.0f, 0.0f);
        if (p < n) v = ((const float2*)xy)[p];
        xyv[pp] = v;
    }
    #pragma unroll
    for (int jj = 0; jj < 4; ++jj) {
        int j = j0 + jj;
        float wx = W0[j];
        float wy = W0[HID + j];
        float bb = b0[j];
        float s2 = fmaf(wx, wx, wy * wy);
        float4 v, ax, ay, al;
        #pragma unroll
        for (int pp = 0; pp < 4; ++pp) {
            float z = fmaf(xyv[pp].x, wx, fmaf(xyv[pp].y, wy, bb));
            float a = fast_tanh(z);
            float t = fmaf(-a, a, 1.0f);
            (&v.x)[pp] = a;
            if (INTERIOR) {
                (&ax.x)[pp] = t * wx;                  // z_x = wx (const), z_lap = 0
                (&ay.x)[pp] = t * wy;
                (&al.x)[pp] = -2.0f * a * t * s2;
            }
        }
        float* row = sA + j * SA_STR + p0;
        *(float4*)row = v;
        if (INTERIOR) {
            *(float4*)(row + HID * SA_STR) = ax;
            *(float4*)(row + 2 * HID * SA_STR) = ay;
            *(float4*)(row + 3 * HID * SA_STR) = al;
        }
    }
    #pragma unroll
    for (int i = 0; i < 16; ++i)
        ((float4*)sW)[i * 256 + tid] = wst[i];
    __syncthreads();

    // ---- hidden layers 1,2: Z^T[j][p] = sum_k W[k][j] * A^T[k][p] ----
    #pragma unroll 1
    for (int L = 0; L < 2; ++L) {
        float4 acc[NC][4];
        #pragma unroll
        for (int c = 0; c < NC; ++c)
            #pragma unroll
            for (int jj = 0; jj < 4; ++jj)
                acc[c][jj] = make_float4(0.0f, 0.0f, 0.0f, 0.0f);

        #pragma unroll 4
        for (int k = 0; k < HID; ++k) {
            float4 wv = *(const float4*)(sW + k * HID + j0);
            float4 av[NC];
            #pragma unroll
            for (int c = 0; c < NC; ++c)
                av[c] = *(const float4*)(sA + (c * HID + k) * SA_STR + p0);
            #pragma unroll
            for (int jj = 0; jj < 4; ++jj) {
                float w = (&wv.x)[jj];
                #pragma unroll
                for (int c = 0; c < NC; ++c)
                    #pragma unroll
                    for (int pp = 0; pp < 4; ++pp)
                        (&acc[c][jj].x)[pp] =
                            fmaf((&av[c].x)[pp], w, (&acc[c][jj].x)[pp]);
            }
        }

        if (L == 0) {  // issue W2 loads before the barrier; store after
            #pragma unroll
            for (int i = 0; i < 16; ++i)
                wst[i] = ((const float4*)W2)[i * 256 + tid];
        }
        __syncthreads();  // all reads of sA/sW complete

        const float* bptr = (L == 0) ? b1 : b2;
        #pragma unroll
        for (int jj = 0; jj < 4; ++jj) {
            int j = j0 + jj;
            float bb = bptr[j];
            float4 v, ax, ay, al;
            #pragma unroll
            for (int pp = 0; pp < 4; ++pp) {
                float z = (&acc[0][jj].x)[pp] + bb;
                float a = fast_tanh(z);
                float t = fmaf(-a, a, 1.0f);
                (&v.x)[pp] = a;
                if (INTERIOR) {
                    float zx = (&acc[1][jj].x)[pp];
                    float zy = (&acc[2][jj].x)[pp];
                    float zl = (&acc[3][jj].x)[pp];
                    float s2 = fmaf(zx, zx, zy * zy);
                    (&ax.x)[pp] = t * zx;
                    (&ay.x)[pp] = t * zy;
                    // lap(a) = t*lap(z) - 2*a*t*(zx^2+zy^2)
                    (&al.x)[pp] = fmaf(t, zl, -2.0f * a * t * s2);
                }
            }
            float* row = sA + j * SA_STR + p0;
            *(float4*)row = v;
            if (INTERIOR) {
                *(float4*)(row + HID * SA_STR) = ax;
                *(float4*)(row + 2 * HID * SA_STR) = ay;
                *(float4*)(row + 3 * HID * SA_STR) = al;
            }
        }
        if (L == 0) {
            #pragma unroll
            for (int i = 0; i < 16; ++i)
                ((float4*)sW)[i * 256 + tid] = wst[i];
        }
        __syncthreads();
    }

    // ---- readout: interior uses laplacian channel, boundary uses value ----
    constexpr int rc = INTERIOR ? 3 : 0;
    float w3v[4];
    #pragma unroll
    for (int jj = 0; jj < 4; ++jj) w3v[jj] = W3[j0 + jj];
    float4 r = make_float4(0.0f, 0.0f, 0.0f, 0.0f);
    #pragma unroll
    for (int jj = 0; jj < 4; ++jj) {
        float4 a = *(const float4*)(sA + (rc * HID + j0 + jj) * SA_STR + p0);
        #pragma unroll
        for (int pp = 0; pp < 4; ++pp)
            (&r.x)[pp] = fmaf((&a.x)[pp], w3v[jj], (&r.x)[pp]);
    }
    // reduce over the 32 tj lanes (each 32-lane half of the wave = one tp group)
    #pragma unroll
    for (int m = 1; m < 32; m <<= 1) {
        r.x += __shfl_xor(r.x, m, 64);
        r.y += __shfl_xor(r.y, m, 64);
        r.z += __shfl_xor(r.z, m, 64);
        r.w += __shfl_xor(r.w, m, 64);
    }
    if (tj == 0) {
        float bb3 = INTERIOR ? 0.0f : b3[0];  // bias cancels in laplacian
        float term = 0.0f;
        #pragma unroll
        for (int pp = 0; pp < 4; ++pp) {
            int p = pbase + p0 + pp;
            if (p < n) {
                float d = (&r.x)[pp] + bb3 - tgt[p];
                term = fmaf(d, d, term);
            }
        }
        sRed[tp] = term;
    }
    __syncthreads();
    if (tid == 0) {
        float s = 0.0f;
        #pragma unroll
        for (int i = 0; i < 8; ++i) s += sRed[i];
        atomicAdd(out_slot, s * scale);
    }
}

extern "C" void kernel_launch(void* const* d_in, const int* in_sizes, int n_in,
                              void* d_out, int out_size, void* d_ws, size_t ws_size,
                              hipStream_t stream) {
    const float* xy_int = (const float*)d_in[0];
    const float* f      = (const float*)d_in[1];
    const float* xy_bd  = (const float*)d_in[2];
    const float* g      = (const float*)d_in[3];
    const float* W0 = (const float*)d_in[4];
    const float* b0 = (const float*)d_in[5];
    const float* W1 = (const float*)d_in[6];
    const float* b1 = (const float*)d_in[7];
    const float* W2 = (const float*)d_in[8];
    const float* b2 = (const float*)d_in[9];
    const float* W3 = (const float*)d_in[10];
    const float* b3 = (const float*)d_in[11];
    float* out = (float*)d_out;

    const int n_int = in_sizes[0] / 2;
    const int n_bd  = in_sizes[2] / 2;

    zero_out_kernel<<<1, 64, 0, stream>>>(out);

    const int smem_int = (HID * HID + 4 * HID * SA_STR + 8) * (int)sizeof(float);
    const int smem_bd  = (HID * HID + 1 * HID * SA_STR + 8) * (int)sizeof(float);
    const int gi = (n_int + PTS - 1) / PTS;
    const int gb = (n_bd + PTS - 1) / PTS;

    pinn_mlp_kernel<true><<<gi, 256, smem_int, stream>>>(
        xy_int, f, W0, b0, W1, b1, W2, b2, W3, b3,
        out + 1, n_int, 0.5f / (float)n_int);
    pinn_mlp_kernel<false><<<gb, 256, smem_bd, stream>>>(
        xy_bd, g, W0, b0, W1, b1, W2, b2, W3, b3,
        out + 0, n_bd, 0.5f / (float)n_bd);
}

// Round 2
// 1219.664 us; speedup vs baseline: 1.1617x; 1.1617x over previous
//
#include <hip/hip_runtime.h>

#define HID 128
#define PTS 32      // points per block
#define SA_STR 36   // padded p-stride (multiple of 4 -> 16B-aligned rows)

typedef float v4 __attribute__((ext_vector_type(4)));   // true vector: SROA-proof
typedef float v2 __attribute__((ext_vector_type(2)));

// tanh(x) = 1 - 2/(exp(2x)+1); v_exp + v_rcp, correct limits at +-inf
__device__ __forceinline__ float fast_tanh(float x) {
    float e = __expf(2.0f * x);
    float r = __builtin_amdgcn_rcpf(e + 1.0f);
    return 1.0f - 2.0f * r;
}

// async global->LDS DMA, 16B per lane; lds dest = wave-uniform base + lane*16
__device__ __forceinline__ void lds_dma16(const float* g, float* l) {
    __builtin_amdgcn_global_load_lds(
        (const __attribute__((address_space(1))) float*)g,
        (__attribute__((address_space(3))) float*)l, 16, 0, 0);
}

// copy HID*HID fp32 (64 KB) global -> LDS, contiguous, via LDS-DMA (no VGPR staging)
__device__ __forceinline__ void copy_w_lds(const float* __restrict__ W,
                                           float* sW, int tid) {
    const int wave_off = tid & ~63;  // 64 * wave_id  (float4-unit offset base)
    const int lane = tid & 63;
    #pragma unroll
    for (int i = 0; i < 16; ++i) {
        const int base4 = i * 256 + wave_off;          // float4 index, wave-uniform
        lds_dma16(W + (base4 + lane) * 4, sW + base4 * 4);
    }
}

__global__ void zero_out_kernel(float* out) {
    if (threadIdx.x < 2) out[threadIdx.x] = 0.0f;
}

// One block processes PTS=32 points through the whole MLP.
// Channels: 0=value, 1=d/dx, 2=d/dy, 3=laplacian (INTERIOR only).
// Thread tile: tj = tid&31 -> 4 j-columns, tp = tid>>5 -> 4 points.
template <bool INTERIOR>
__global__ __launch_bounds__(256, 1) void pinn_mlp_kernel(
    const float* __restrict__ xy, const float* __restrict__ tgt,
    const float* __restrict__ W0, const float* __restrict__ b0,
    const float* __restrict__ W1, const float* __restrict__ b1,
    const float* __restrict__ W2, const float* __restrict__ b2,
    const float* __restrict__ W3, const float* __restrict__ b3,
    float* __restrict__ out_slot, int n, float scale)
{
    constexpr int NC = INTERIOR ? 4 : 1;
    extern __shared__ float smem[];
    float* sW = smem;                      // HID*HID fp32 (64 KB), current layer W
    float* sA = smem + HID * HID;          // NC * HID * SA_STR, k-major activations
    float* sRed = sA + NC * HID * SA_STR;  // 8 floats

    const int tid = threadIdx.x;
    const int tj = tid & 31;
    const int tp = tid >> 5;
    const int j0 = tj * 4;
    const int p0 = tp * 4;
    const int pbase = blockIdx.x * PTS;

    // ---- start W1 DMA into LDS immediately (overlaps layer-0 math) ----
    copy_w_lds(W1, sW, tid);

    // ---- layer 0: 2 -> 128 ----
    v2 xyv[4];
    #pragma unroll
    for (int pp = 0; pp < 4; ++pp) {
        int p = pbase + p0 + pp;
        v2 v = {0.0f, 0.0f};
        if (p < n) {
            float2 t = ((const float2*)xy)[p];
            v[0] = t.x; v[1] = t.y;
        }
        xyv[pp] = v;
    }
    #pragma unroll
    for (int jj = 0; jj < 4; ++jj) {
        int j = j0 + jj;
        float wx = W0[j];
        float wy = W0[HID + j];
        float bb = b0[j];
        float s2 = fmaf(wx, wx, wy * wy);
        v4 v, ax, ay, al;
        #pragma unroll
        for (int pp = 0; pp < 4; ++pp) {
            float z = fmaf(xyv[pp][0], wx, fmaf(xyv[pp][1], wy, bb));
            float a = fast_tanh(z);
            float t = fmaf(-a, a, 1.0f);
            v[pp] = a;
            if (INTERIOR) {
                ax[pp] = t * wx;                 // z_x = wx (const), z_lap = 0
                ay[pp] = t * wy;
                al[pp] = -2.0f * a * t * s2;
            }
        }
        float* row = sA + j * SA_STR + p0;
        *(v4*)row = v;
        if (INTERIOR) {
            *(v4*)(row + HID * SA_STR) = ax;
            *(v4*)(row + 2 * HID * SA_STR) = ay;
            *(v4*)(row + 3 * HID * SA_STR) = al;
        }
    }
    __syncthreads();   // waits vmcnt(0): W1 resident; sA(layer0) visible

    // ---- hidden layers 1,2: Z^T[j][p] = sum_k W[k][j] * A^T[k][p] ----
    #pragma unroll 1
    for (int L = 0; L < 2; ++L) {
        v4 acc[NC][4];
        #pragma unroll
        for (int c = 0; c < NC; ++c)
            #pragma unroll
            for (int jj = 0; jj < 4; ++jj)
                acc[c][jj] = (v4){0.0f, 0.0f, 0.0f, 0.0f};

        #pragma unroll 4
        for (int k = 0; k < HID; ++k) {
            v4 wv = *(const v4*)(sW + k * HID + j0);
            v4 av[NC];
            #pragma unroll
            for (int c = 0; c < NC; ++c)
                av[c] = *(const v4*)(sA + (c * HID + k) * SA_STR + p0);
            #pragma unroll
            for (int jj = 0; jj < 4; ++jj)
                #pragma unroll
                for (int c = 0; c < NC; ++c)
                    #pragma unroll
                    for (int pp = 0; pp < 4; ++pp)
                        acc[c][jj][pp] = fmaf(av[c][pp], wv[jj], acc[c][jj][pp]);
        }
        __syncthreads();  // all reads of sA/sW complete

        if (L == 0)
            copy_w_lds(W2, sW, tid);   // async DMA overlaps the tanh epilogue

        const float* bptr = (L == 0) ? b1 : b2;
        #pragma unroll
        for (int jj = 0; jj < 4; ++jj) {
            int j = j0 + jj;
            float bb = bptr[j];
            v4 v, ax, ay, al;
            #pragma unroll
            for (int pp = 0; pp < 4; ++pp) {
                float z = acc[0][jj][pp] + bb;
                float a = fast_tanh(z);
                float t = fmaf(-a, a, 1.0f);
                v[pp] = a;
                if (INTERIOR) {
                    float zx = acc[1][jj][pp];
                    float zy = acc[2][jj][pp];
                    float zl = acc[3][jj][pp];
                    float s2 = fmaf(zx, zx, zy * zy);
                    ax[pp] = t * zx;
                    ay[pp] = t * zy;
                    // lap(a) = t*lap(z) - 2*a*t*(zx^2+zy^2)
                    al[pp] = fmaf(t, zl, -2.0f * a * t * s2);
                }
            }
            float* row = sA + j * SA_STR + p0;
            *(v4*)row = v;
            if (INTERIOR) {
                *(v4*)(row + HID * SA_STR) = ax;
                *(v4*)(row + 2 * HID * SA_STR) = ay;
                *(v4*)(row + 3 * HID * SA_STR) = al;
            }
        }
        __syncthreads();   // vmcnt(0) drained: W2 resident; new sA visible
    }

    // ---- readout: interior uses laplacian channel, boundary uses value ----
    constexpr int rc = INTERIOR ? 3 : 0;
    float w3v[4];
    #pragma unroll
    for (int jj = 0; jj < 4; ++jj) w3v[jj] = W3[j0 + jj];
    v4 r = {0.0f, 0.0f, 0.0f, 0.0f};
    #pragma unroll
    for (int jj = 0; jj < 4; ++jj) {
        v4 a = *(const v4*)(sA + (rc * HID + j0 + jj) * SA_STR + p0);
        #pragma unroll
        for (int pp = 0; pp < 4; ++pp)
            r[pp] = fmaf(a[pp], w3v[jj], r[pp]);
    }
    // reduce over the 32 tj lanes (each 32-lane half of the wave = one tp group)
    #pragma unroll
    for (int m = 1; m < 32; m <<= 1) {
        r[0] += __shfl_xor(r[0], m, 64);
        r[1] += __shfl_xor(r[1], m, 64);
        r[2] += __shfl_xor(r[2], m, 64);
        r[3] += __shfl_xor(r[3], m, 64);
    }
    if (tj == 0) {
        float bb3 = INTERIOR ? 0.0f : b3[0];  // bias cancels in laplacian
        float term = 0.0f;
        #pragma unroll
        for (int pp = 0; pp < 4; ++pp) {
            int p = pbase + p0 + pp;
            if (p < n) {
                float d = r[pp] + bb3 - tgt[p];
                term = fmaf(d, d, term);
            }
        }
        sRed[tp] = term;
    }
    __syncthreads();
    if (tid == 0) {
        float s = 0.0f;
        #pragma unroll
        for (int i = 0; i < 8; ++i) s += sRed[i];
        atomicAdd(out_slot, s * scale);
    }
}

extern "C" void kernel_launch(void* const* d_in, const int* in_sizes, int n_in,
                              void* d_out, int out_size, void* d_ws, size_t ws_size,
                              hipStream_t stream) {
    const float* xy_int = (const float*)d_in[0];
    const float* f      = (const float*)d_in[1];
    const float* xy_bd  = (const float*)d_in[2];
    const float* g      = (const float*)d_in[3];
    const float* W0 = (const float*)d_in[4];
    const float* b0 = (const float*)d_in[5];
    const float* W1 = (const float*)d_in[6];
    const float* b1 = (const float*)d_in[7];
    const float* W2 = (const float*)d_in[8];
    const float* b2 = (const float*)d_in[9];
    const float* W3 = (const float*)d_in[10];
    const float* b3 = (const float*)d_in[11];
    float* out = (float*)d_out;

    const int n_int = in_sizes[0] / 2;
    const int n_bd  = in_sizes[2] / 2;

    zero_out_kernel<<<1, 64, 0, stream>>>(out);

    const int smem_int = (HID * HID + 4 * HID * SA_STR + 8) * (int)sizeof(float);
    const int smem_bd  = (HID * HID + 1 * HID * SA_STR + 8) * (int)sizeof(float);
    const int gi = (n_int + PTS - 1) / PTS;
    const int gb = (n_bd + PTS - 1) / PTS;

    pinn_mlp_kernel<true><<<gi, 256, smem_int, stream>>>(
        xy_int, f, W0, b0, W1, b1, W2, b2, W3, b3,
        out + 1, n_int, 0.5f / (float)n_int);
    pinn_mlp_kernel<false><<<gb, 256, smem_bd, stream>>>(
        xy_bd, g, W0, b0, W1, b1, W2, b2, W3, b3,
        out + 0, n_bd, 0.5f / (float)n_bd);
}

// Round 3
// 887.239 us; speedup vs baseline: 1.5969x; 1.3747x over previous
//
#include <hip/hip_runtime.h>

#define HID 128
#define PTS 32      // points per block
#define SA_STR 36   // padded p-stride (multiple of 4 -> 16B-aligned rows)

typedef float v4 __attribute__((ext_vector_type(4)));   // true vector: SROA-proof
typedef float v2 __attribute__((ext_vector_type(2)));

// tanh(x) = 1 - 2/(exp(2x)+1); v_exp + v_rcp, correct limits at +-inf
__device__ __forceinline__ float fast_tanh(float x) {
    float e = __expf(2.0f * x);
    float r = __builtin_amdgcn_rcpf(e + 1.0f);
    return 1.0f - 2.0f * r;
}

__global__ void zero_out_kernel(float* out) {
    if (threadIdx.x < 2) out[threadIdx.x] = 0.0f;
}

// One block processes PTS=32 points through the whole MLP.
// Channels: 0=value, 1=d/dx, 2=d/dy, 3=laplacian (INTERIOR only).
// Thread tile: tj = tid&31 -> 4 j-columns, tp = tid>>5 -> 4 points.
// Weights are read straight from global (L2-resident, 512 B/wave/k,
// broadcast-coalesced) -- keeps LDS at 74 KB so 2 blocks/CU co-reside.
template <bool INTERIOR>
__global__ __launch_bounds__(256, 2) void pinn_mlp_kernel(
    const float* __restrict__ xy, const float* __restrict__ tgt,
    const float* __restrict__ W0, const float* __restrict__ b0,
    const float* __restrict__ W1, const float* __restrict__ b1,
    const float* __restrict__ W2, const float* __restrict__ b2,
    const float* __restrict__ W3, const float* __restrict__ b3,
    float* __restrict__ out_slot, int n, float scale)
{
    constexpr int NC = INTERIOR ? 4 : 1;
    extern __shared__ float smem[];
    float* sA = smem;                      // NC * HID * SA_STR, k-major activations
    float* sRed = sA + NC * HID * SA_STR;  // 8 floats

    const int tid = threadIdx.x;
    const int tj = tid & 31;
    const int tp = tid >> 5;
    const int j0 = tj * 4;
    const int p0 = tp * 4;
    const int pbase = blockIdx.x * PTS;

    // ---- layer 0: 2 -> 128 ----
    v2 xyv[4];
    #pragma unroll
    for (int pp = 0; pp < 4; ++pp) {
        int p = pbase + p0 + pp;
        v2 v = {0.0f, 0.0f};
        if (p < n) {
            float2 t = ((const float2*)xy)[p];
            v[0] = t.x; v[1] = t.y;
        }
        xyv[pp] = v;
    }
    #pragma unroll
    for (int jj = 0; jj < 4; ++jj) {
        int j = j0 + jj;
        float wx = W0[j];
        float wy = W0[HID + j];
        float bb = b0[j];
        float s2 = fmaf(wx, wx, wy * wy);
        v4 v, ax, ay, al;
        #pragma unroll
        for (int pp = 0; pp < 4; ++pp) {
            float z = fmaf(xyv[pp][0], wx, fmaf(xyv[pp][1], wy, bb));
            float a = fast_tanh(z);
            float t = fmaf(-a, a, 1.0f);
            v[pp] = a;
            if (INTERIOR) {
                ax[pp] = t * wx;                 // z_x = wx (const), z_lap = 0
                ay[pp] = t * wy;
                al[pp] = -2.0f * a * t * s2;
            }
        }
        float* row = sA + j * SA_STR + p0;
        *(v4*)row = v;
        if (INTERIOR) {
            *(v4*)(row + HID * SA_STR) = ax;
            *(v4*)(row + 2 * HID * SA_STR) = ay;
            *(v4*)(row + 3 * HID * SA_STR) = al;
        }
    }
    __syncthreads();   // sA(layer0) visible

    // ---- hidden layers 1,2: Z^T[j][p] = sum_k W[k][j] * A^T[k][p] ----
    #pragma unroll 1
    for (int L = 0; L < 2; ++L) {
        const float* __restrict__ Wcur = (L == 0) ? W1 : W2;
        v4 acc[NC][4];
        #pragma unroll
        for (int c = 0; c < NC; ++c)
            #pragma unroll
            for (int jj = 0; jj < 4; ++jj)
                acc[c][jj] = (v4){0.0f, 0.0f, 0.0f, 0.0f};

        #pragma unroll 8
        for (int k = 0; k < HID; ++k) {
            v4 wv = *(const v4*)(Wcur + k * HID + j0);   // global, L2-resident
            v4 av[NC];
            #pragma unroll
            for (int c = 0; c < NC; ++c)
                av[c] = *(const v4*)(sA + (c * HID + k) * SA_STR + p0);
            #pragma unroll
            for (int jj = 0; jj < 4; ++jj)
                #pragma unroll
                for (int c = 0; c < NC; ++c)
                    #pragma unroll
                    for (int pp = 0; pp < 4; ++pp)
                        acc[c][jj][pp] = fmaf(av[c][pp], wv[jj], acc[c][jj][pp]);
        }
        __syncthreads();  // all reads of sA complete before overwrite

        const float* bptr = (L == 0) ? b1 : b2;
        #pragma unroll
        for (int jj = 0; jj < 4; ++jj) {
            int j = j0 + jj;
            float bb = bptr[j];
            v4 v, ax, ay, al;
            #pragma unroll
            for (int pp = 0; pp < 4; ++pp) {
                float z = acc[0][jj][pp] + bb;
                float a = fast_tanh(z);
                float t = fmaf(-a, a, 1.0f);
                v[pp] = a;
                if (INTERIOR) {
                    float zx = acc[1][jj][pp];
                    float zy = acc[2][jj][pp];
                    float zl = acc[3][jj][pp];
                    float s2 = fmaf(zx, zx, zy * zy);
                    ax[pp] = t * zx;
                    ay[pp] = t * zy;
                    // lap(a) = t*lap(z) - 2*a*t*(zx^2+zy^2)
                    al[pp] = fmaf(t, zl, -2.0f * a * t * s2);
                }
            }
            float* row = sA + j * SA_STR + p0;
            *(v4*)row = v;
            if (INTERIOR) {
                *(v4*)(row + HID * SA_STR) = ax;
                *(v4*)(row + 2 * HID * SA_STR) = ay;
                *(v4*)(row + 3 * HID * SA_STR) = al;
            }
        }
        __syncthreads();   // new sA visible
    }

    // ---- readout: interior uses laplacian channel, boundary uses value ----
    constexpr int rc = INTERIOR ? 3 : 0;
    float w3v[4];
    #pragma unroll
    for (int jj = 0; jj < 4; ++jj) w3v[jj] = W3[j0 + jj];
    v4 r = {0.0f, 0.0f, 0.0f, 0.0f};
    #pragma unroll
    for (int jj = 0; jj < 4; ++jj) {
        v4 a = *(const v4*)(sA + (rc * HID + j0 + jj) * SA_STR + p0);
        #pragma unroll
        for (int pp = 0; pp < 4; ++pp)
            r[pp] = fmaf(a[pp], w3v[jj], r[pp]);
    }
    // reduce over the 32 tj lanes (each 32-lane half of the wave = one tp group)
    #pragma unroll
    for (int m = 1; m < 32; m <<= 1) {
        r[0] += __shfl_xor(r[0], m, 64);
        r[1] += __shfl_xor(r[1], m, 64);
        r[2] += __shfl_xor(r[2], m, 64);
        r[3] += __shfl_xor(r[3], m, 64);
    }
    if (tj == 0) {
        float bb3 = INTERIOR ? 0.0f : b3[0];  // bias cancels in laplacian
        float term = 0.0f;
        #pragma unroll
        for (int pp = 0; pp < 4; ++pp) {
            int p = pbase + p0 + pp;
            if (p < n) {
                float d = r[pp] + bb3 - tgt[p];
                term = fmaf(d, d, term);
            }
        }
        sRed[tp] = term;
    }
    __syncthreads();
    if (tid == 0) {
        float s = 0.0f;
        #pragma unroll
        for (int i = 0; i < 8; ++i) s += sRed[i];
        atomicAdd(out_slot, s * scale);
    }
}

extern "C" void kernel_launch(void* const* d_in, const int* in_sizes, int n_in,
                              void* d_out, int out_size, void* d_ws, size_t ws_size,
                              hipStream_t stream) {
    const float* xy_int = (const float*)d_in[0];
    const float* f      = (const float*)d_in[1];
    const float* xy_bd  = (const float*)d_in[2];
    const float* g      = (const float*)d_in[3];
    const float* W0 = (const float*)d_in[4];
    const float* b0 = (const float*)d_in[5];
    const float* W1 = (const float*)d_in[6];
    const float* b1 = (const float*)d_in[7];
    const float* W2 = (const float*)d_in[8];
    const float* b2 = (const float*)d_in[9];
    const float* W3 = (const float*)d_in[10];
    const float* b3 = (const float*)d_in[11];
    float* out = (float*)d_out;

    const int n_int = in_sizes[0] / 2;
    const int n_bd  = in_sizes[2] / 2;

    zero_out_kernel<<<1, 64, 0, stream>>>(out);

    const int smem_int = (4 * HID * SA_STR + 8) * (int)sizeof(float);
    const int smem_bd  = (1 * HID * SA_STR + 8) * (int)sizeof(float);
    const int gi = (n_int + PTS - 1) / PTS;
    const int gb = (n_bd + PTS - 1) / PTS;

    pinn_mlp_kernel<true><<<gi, 256, smem_int, stream>>>(
        xy_int, f, W0, b0, W1, b1, W2, b2, W3, b3,
        out + 1, n_int, 0.5f / (float)n_int);
    pinn_mlp_kernel<false><<<gb, 256, smem_bd, stream>>>(
        xy_bd, g, W0, b0, W1, b1, W2, b2, W3, b3,
        out + 0, n_bd, 0.5f / (float)n_bd);
}

// Round 4
// 840.829 us; speedup vs baseline: 1.6851x; 1.0552x over previous
//
#include <hip/hip_runtime.h>

#define HID 128
#define PTS 32
#define KP  136   // sB k-row stride in bf16 units (128 + 8 pad: 16B-aligned, conflict-free)

typedef float v4f __attribute__((ext_vector_type(4)));
typedef short s8v __attribute__((ext_vector_type(8)));          // 8 bf16 (MFMA A/B frag)
typedef unsigned short us4v __attribute__((ext_vector_type(4)));

__device__ __forceinline__ unsigned short f2bf(float f) {       // RNE fp32->bf16
    unsigned u = __builtin_bit_cast(unsigned, f);
    u = (u + 0x7FFFu + ((u >> 16) & 1u)) >> 16;
    return (unsigned short)u;
}
__device__ __forceinline__ float bf2f(unsigned short h) {
    unsigned u = ((unsigned)h) << 16;
    return __builtin_bit_cast(float, u);
}
__device__ __forceinline__ float fast_tanh(float x) {
    float e = __expf(2.0f * x);
    float r = __builtin_amdgcn_rcpf(e + 1.0f);
    return 1.0f - 2.0f * r;
}

__global__ void zero_out_kernel(float* out) {
    if (threadIdx.x < 2) out[threadIdx.x] = 0.0f;
}

// Load W fragments (A-operand layout, split hi/lo bf16) for this wave's j-half.
// A[m][k] = W[k][m]; m = mtile*16 + (lane&15), k = ks*32 + quad*8 + i.
__device__ __forceinline__ void load_w_frags(
    const float* __restrict__ W, int mh, int l15, int quad,
    s8v (&whi)[4][4], s8v (&wlo)[4][4])
{
    #pragma unroll
    for (int mt = 0; mt < 4; ++mt)
        #pragma unroll
        for (int ks = 0; ks < 4; ++ks) {
            const int m  = (mh * 4 + mt) * 16 + l15;
            const int kb = ks * 32 + quad * 8;
            float f[8];
            #pragma unroll
            for (int i = 0; i < 8; ++i)
                f[i] = W[(kb + i) * HID + m];
            s8v h, l;
            #pragma unroll
            for (int i = 0; i < 8; ++i) {
                unsigned short hh = f2bf(f[i]);
                h[i] = (short)hh;
                l[i] = (short)f2bf(f[i] - bf2f(hh));
            }
            whi[mt][ks] = h;
            wlo[mt][ks] = l;
        }
}

// One block = 32 points. Hidden layers via split-bf16 MFMA (3 products ~ fp32).
// Cols n = c*32 + p (c: 0=val,1=dx,2=dy,3=lap). Wave grid: (j-half mh) x (p-half pt).
// C/D layout (m89): col=lane&15, row=quad*4+reg -> all 4 channels of (j,p) in one lane.
template <int NC>
__global__ __launch_bounds__(256, 2) void pinn_mfma_kernel(
    const float* __restrict__ xy, const float* __restrict__ tgt,
    const float* __restrict__ W0, const float* __restrict__ b0,
    const float* __restrict__ W1, const float* __restrict__ b1,
    const float* __restrict__ W2, const float* __restrict__ b2,
    const float* __restrict__ W3, const float* __restrict__ b3,
    float* __restrict__ out_slot, float scale)
{
    constexpr int RC = (NC == 4) ? 3 : 0;     // readout channel
    extern __shared__ char smem_raw[];
    unsigned short* sBh = (unsigned short*)smem_raw;     // [NC*32][KP] bf16 hi
    unsigned short* sBl = sBh + NC * 32 * KP;            // [NC*32][KP] bf16 lo
    float* sRed = (float*)(sBl + NC * 32 * KP);          // [PTS]

    const int tid   = threadIdx.x;
    const int lane  = tid & 63;
    const int wave  = tid >> 6;
    const int l15   = lane & 15;
    const int quad  = lane >> 4;
    const int mh    = wave & 1;     // j-half: m-tiles mh*4..mh*4+3
    const int pt    = wave >> 1;    // p-half: cols pt*16..pt*16+15
    const int pbase = blockIdx.x * PTS;

    // ---- W1 fragments -> registers (issue first: long-latency L2 loads) ----
    s8v whi[4][4], wlo[4][4];       // [mt][ks]
    load_w_frags(W1, mh, l15, quad, whi, wlo);

    // ---- layer 0: 2 -> 128, VALU, store split-bf16 into sB ----
    {
        const int tj = tid & 31, tp = tid >> 5;
        const int j0 = tj * 4, p0 = tp * 4;
        float wx[4], wy[4], bb[4];
        #pragma unroll
        for (int jj = 0; jj < 4; ++jj) {
            wx[jj] = W0[j0 + jj];
            wy[jj] = W0[HID + j0 + jj];
            bb[jj] = b0[j0 + jj];
        }
        #pragma unroll
        for (int pp = 0; pp < 4; ++pp) {
            const int p = p0 + pp;
            const float2 t2 = ((const float2*)xy)[pbase + p];
            unsigned short hk[NC][4], lk[NC][4];
            #pragma unroll
            for (int jj = 0; jj < 4; ++jj) {
                float z = fmaf(t2.x, wx[jj], fmaf(t2.y, wy[jj], bb[jj]));
                float a = fast_tanh(z);
                float t = fmaf(-a, a, 1.0f);
                float ch[NC];
                ch[0] = a;
                if (NC == 4) {
                    float s2 = fmaf(wx[jj], wx[jj], wy[jj] * wy[jj]);
                    ch[1] = t * wx[jj];
                    ch[2] = t * wy[jj];
                    ch[3] = -2.0f * a * t * s2;      // z_lap = 0 at layer 0
                }
                #pragma unroll
                for (int c = 0; c < NC; ++c) {
                    unsigned short hh = f2bf(ch[c]);
                    hk[c][jj] = hh;
                    lk[c][jj] = f2bf(ch[c] - bf2f(hh));
                }
            }
            #pragma unroll
            for (int c = 0; c < NC; ++c) {
                const int row = (c * 32 + p) * KP + j0;
                us4v hv = {hk[c][0], hk[c][1], hk[c][2], hk[c][3]};
                us4v lv = {lk[c][0], lk[c][1], lk[c][2], lk[c][3]};
                *(us4v*)&sBh[row] = hv;
                *(us4v*)&sBl[row] = lv;
            }
        }
    }
    __syncthreads();

    // ---- hidden layers: D = W^T(A-op) x Act(B-op), 3-product split-bf16 ----
    #pragma unroll
    for (int L = 0; L < 2; ++L) {
        v4f acc[4][NC];   // [mt][c]
        #pragma unroll
        for (int mt = 0; mt < 4; ++mt)
            #pragma unroll
            for (int c = 0; c < NC; ++c)
                acc[mt][c] = (v4f){0.0f, 0.0f, 0.0f, 0.0f};

        #pragma unroll
        for (int c = 0; c < NC; ++c) {
            const int nt = c * 2 + pt;
            const int rb = (nt * 16 + l15) * KP + quad * 8;
            #pragma unroll
            for (int ks = 0; ks < 4; ++ks) {
                s8v bh = *(const s8v*)&sBh[rb + ks * 32];
                s8v bl = *(const s8v*)&sBl[rb + ks * 32];
                #pragma unroll
                for (int mt = 0; mt < 4; ++mt)
                    acc[mt][c] = __builtin_amdgcn_mfma_f32_16x16x32_bf16(
                        whi[mt][ks], bh, acc[mt][c], 0, 0, 0);
                #pragma unroll
                for (int mt = 0; mt < 4; ++mt)
                    acc[mt][c] = __builtin_amdgcn_mfma_f32_16x16x32_bf16(
                        whi[mt][ks], bl, acc[mt][c], 0, 0, 0);
                #pragma unroll
                for (int mt = 0; mt < 4; ++mt)
                    acc[mt][c] = __builtin_amdgcn_mfma_f32_16x16x32_bf16(
                        wlo[mt][ks], bh, acc[mt][c], 0, 0, 0);
            }
        }
        __syncthreads();            // all waves done reading sB

        if (L == 0)                 // W2 loads overlap the epilogue below
            load_w_frags(W2, mh, l15, quad, whi, wlo);

        const float* __restrict__ bptr = (L == 0) ? b1 : b2;
        #pragma unroll
        for (int mt = 0; mt < 4; ++mt) {
            const int jb = (mh * 4 + mt) * 16 + quad * 4;   // 4 consecutive j
            unsigned short hk[NC][4], lk[NC][4];
            #pragma unroll
            for (int r = 0; r < 4; ++r) {
                float z = acc[mt][0][r] + bptr[jb + r];
                float a = fast_tanh(z);
                float t = fmaf(-a, a, 1.0f);
                float ch[NC];
                ch[0] = a;
                if (NC == 4) {
                    float zx = acc[mt][1][r], zy = acc[mt][2][r], zl = acc[mt][3][r];
                    float s2 = fmaf(zx, zx, zy * zy);
                    ch[1] = t * zx;
                    ch[2] = t * zy;
                    ch[3] = fmaf(t, zl, -2.0f * a * t * s2);
                }
                #pragma unroll
                for (int c = 0; c < NC; ++c) {
                    unsigned short hh = f2bf(ch[c]);
                    hk[c][r] = hh;
                    lk[c][r] = f2bf(ch[c] - bf2f(hh));
                }
            }
            #pragma unroll
            for (int c = 0; c < NC; ++c) {
                if (L == 1 && c != RC) continue;    // last layer: only readout channel
                const int row = (c * 32 + pt * 16 + l15) * KP + jb;
                us4v hv = {hk[c][0], hk[c][1], hk[c][2], hk[c][3]};
                us4v lv = {lk[c][0], lk[c][1], lk[c][2], lk[c][3]};
                *(us4v*)&sBh[row] = hv;
                *(us4v*)&sBl[row] = lv;
            }
        }
        __syncthreads();
    }

    // ---- readout: dot with W3 over k, 8 lanes per point ----
    {
        const int p  = tid >> 3;
        const int i  = tid & 7;
        const int k0 = i * 16;
        const int row = (RC * 32 + p) * KP + k0;
        float r = 0.0f;
        #pragma unroll
        for (int h = 0; h < 2; ++h) {
            s8v vh = *(const s8v*)&sBh[row + h * 8];
            s8v vl = *(const s8v*)&sBl[row + h * 8];
            #pragma unroll
            for (int t = 0; t < 8; ++t) {
                float av = bf2f((unsigned short)vh[t]) + bf2f((unsigned short)vl[t]);
                r = fmaf(av, W3[k0 + h * 8 + t], r);
            }
        }
        r += __shfl_xor(r, 1, 64);
        r += __shfl_xor(r, 2, 64);
        r += __shfl_xor(r, 4, 64);
        if (i == 0) {
            float d = r + ((NC == 1) ? b3[0] : 0.0f) - tgt[pbase + p];  // lap kills b3
            sRed[p] = d * d;
        }
    }
    __syncthreads();
    if (tid == 0) {
        float s = 0.0f;
        #pragma unroll
        for (int p = 0; p < PTS; ++p) s += sRed[p];
        atomicAdd(out_slot, s * scale);
    }
}

extern "C" void kernel_launch(void* const* d_in, const int* in_sizes, int n_in,
                              void* d_out, int out_size, void* d_ws, size_t ws_size,
                              hipStream_t stream) {
    const float* xy_int = (const float*)d_in[0];
    const float* f      = (const float*)d_in[1];
    const float* xy_bd  = (const float*)d_in[2];
    const float* g      = (const float*)d_in[3];
    const float* W0 = (const float*)d_in[4];
    const float* b0 = (const float*)d_in[5];
    const float* W1 = (const float*)d_in[6];
    const float* b1 = (const float*)d_in[7];
    const float* W2 = (const float*)d_in[8];
    const float* b2 = (const float*)d_in[9];
    const float* W3 = (const float*)d_in[10];
    const float* b3 = (const float*)d_in[11];
    float* out = (float*)d_out;

    const int n_int = in_sizes[0] / 2;   // 262144
    const int n_bd  = in_sizes[2] / 2;   // 16384

    zero_out_kernel<<<1, 64, 0, stream>>>(out);

    const int smem_int = (2 * 4 * 32 * KP) * 2 + PTS * 4;  // 69,760 B -> 2 blocks/CU
    const int smem_bd  = (2 * 1 * 32 * KP) * 2 + PTS * 4;  // 17,536 B
    const int gi = n_int / PTS;
    const int gb = n_bd / PTS;

    pinn_mfma_kernel<4><<<gi, 256, smem_int, stream>>>(
        xy_int, f, W0, b0, W1, b1, W2, b2, W3, b3,
        out + 1, 0.5f / (float)n_int);
    pinn_mfma_kernel<1><<<gb, 256, smem_bd, stream>>>(
        xy_bd, g, W0, b0, W1, b1, W2, b2, W3, b3,
        out + 0, 0.5f / (float)n_bd);
}

// Round 5
// 314.669 us; speedup vs baseline: 4.5027x; 2.6721x over previous
//
#include <hip/hip_runtime.h>

#define HID 128
#define PTS 32
#define KP  136   // sB k-row stride in bf16 units (128 + 8 pad)
#define FRAGS_PER_W 2048           // 8 mtg * 4 ks * 64 lanes
#define WS_ELEMS (FRAGS_PER_W * 8) // ushorts per (w, hi/lo) plane

typedef float v4f __attribute__((ext_vector_type(4)));
typedef short s8v __attribute__((ext_vector_type(8)));          // 8 bf16 (MFMA A/B frag)
typedef unsigned short us4v __attribute__((ext_vector_type(4)));

__device__ __forceinline__ unsigned short f2bf(float f) {       // RNE fp32->bf16
    unsigned u = __builtin_bit_cast(unsigned, f);
    u = (u + 0x7FFFu + ((u >> 16) & 1u)) >> 16;
    return (unsigned short)u;
}
__device__ __forceinline__ float bf2f(unsigned short h) {
    unsigned u = ((unsigned)h) << 16;
    return __builtin_bit_cast(float, u);
}
__device__ __forceinline__ float fast_tanh(float x) {
    float e = __expf(2.0f * x);
    float r = __builtin_amdgcn_rcpf(e + 1.0f);
    return 1.0f - 2.0f * r;
}

__global__ void zero_out_kernel(float* out) {
    if (threadIdx.x < 2) out[threadIdx.x] = 0.0f;
}

// One-time (per launch) W1/W2 -> split-bf16 A-fragments, frag-linear in d_ws.
// ws plane order: [W1hi][W1lo][W2hi][W2lo]; frag idx r = mtg*256 + ks*64 + lane.
__global__ __launch_bounds__(256) void prep_w_kernel(
    const float* __restrict__ W1, const float* __restrict__ W2,
    unsigned short* __restrict__ ws)
{
    const int t = blockIdx.x * 256 + threadIdx.x;   // 0..4095
    const int w = t >> 11;
    const int r = t & 2047;
    const int mtg = r >> 8;
    const int ks = (r >> 6) & 3;
    const int lane = r & 63;
    const int m = mtg * 16 + (lane & 15);
    const int kb = ks * 32 + (lane >> 4) * 8;
    const float* W = w ? W2 : W1;
    s8v hv, lv;
    #pragma unroll
    for (int i = 0; i < 8; ++i) {
        float f = W[(kb + i) * HID + m];            // A[m][k] = W[k][m]
        unsigned short hh = f2bf(f);
        hv[i] = (short)hh;
        lv[i] = (short)f2bf(f - bf2f(hh));
    }
    *(s8v*)&ws[((size_t)(w * 2 + 0) * FRAGS_PER_W + r) * 8] = hv;
    *(s8v*)&ws[((size_t)(w * 2 + 1) * FRAGS_PER_W + r) * 8] = lv;
}

// One block = 32 points. Hidden layers via split-bf16 MFMA (3 products ~ fp32).
// Cols n = c*32 + p (c: 0=val,1=dx,2=dy,3=lap). Wave grid: (j-half mh) x (p-half pt).
// C/D layout (m89): col=lane&15, row=quad*4+reg -> all 4 channels of (j,p) in one lane.
// W frags come pre-split from d_ws (L2-resident), double-buffered per ks stage:
// peak regs ~ 64 (W dbuf) + 64 (acc) -> no spill (round-4 spilled at 128+64).
template <int NC>
__global__ __launch_bounds__(256, 2) void pinn_mfma_kernel(
    const float* __restrict__ xy, const float* __restrict__ tgt,
    const float* __restrict__ W0, const float* __restrict__ b0,
    const float* __restrict__ b1, const float* __restrict__ b2,
    const float* __restrict__ W3, const float* __restrict__ b3,
    const unsigned short* __restrict__ ws,
    float* __restrict__ out_slot, float scale)
{
    constexpr int RC = (NC == 4) ? 3 : 0;     // readout channel
    extern __shared__ char smem_raw[];
    unsigned short* sBh = (unsigned short*)smem_raw;     // [NC*32][KP] bf16 hi
    unsigned short* sBl = sBh + NC * 32 * KP;            // [NC*32][KP] bf16 lo
    float* sRed = (float*)(sBl + NC * 32 * KP);          // [PTS]

    const int tid   = threadIdx.x;
    const int lane  = tid & 63;
    const int wave  = tid >> 6;
    const int l15   = lane & 15;
    const int quad  = lane >> 4;
    const int mh    = wave & 1;     // j-half: m-tiles mh*4..mh*4+3
    const int pt    = wave >> 1;    // p-half: cols pt*16..pt*16+15
    const int pbase = blockIdx.x * PTS;

    // ---- layer 0: 2 -> 128, VALU, store split-bf16 into sB ----
    {
        const int tj = tid & 31, tp = tid >> 5;
        const int j0 = tj * 4, p0 = tp * 4;
        float wx[4], wy[4], bb[4];
        #pragma unroll
        for (int jj = 0; jj < 4; ++jj) {
            wx[jj] = W0[j0 + jj];
            wy[jj] = W0[HID + j0 + jj];
            bb[jj] = b0[j0 + jj];
        }
        #pragma unroll
        for (int pp = 0; pp < 4; ++pp) {
            const int p = p0 + pp;
            const float2 t2 = ((const float2*)xy)[pbase + p];
            unsigned short hk[NC][4], lk[NC][4];
            #pragma unroll
            for (int jj = 0; jj < 4; ++jj) {
                float z = fmaf(t2.x, wx[jj], fmaf(t2.y, wy[jj], bb[jj]));
                float a = fast_tanh(z);
                float t = fmaf(-a, a, 1.0f);
                float ch[NC];
                ch[0] = a;
                if (NC == 4) {
                    float s2 = fmaf(wx[jj], wx[jj], wy[jj] * wy[jj]);
                    ch[1] = t * wx[jj];
                    ch[2] = t * wy[jj];
                    ch[3] = -2.0f * a * t * s2;      // z_lap = 0 at layer 0
                }
                #pragma unroll
                for (int c = 0; c < NC; ++c) {
                    unsigned short hh = f2bf(ch[c]);
                    hk[c][jj] = hh;
                    lk[c][jj] = f2bf(ch[c] - bf2f(hh));
                }
            }
            #pragma unroll
            for (int c = 0; c < NC; ++c) {
                const int row = (c * 32 + p) * KP + j0;
                us4v hv = {hk[c][0], hk[c][1], hk[c][2], hk[c][3]};
                us4v lv = {lk[c][0], lk[c][1], lk[c][2], lk[c][3]};
                *(us4v*)&sBh[row] = hv;
                *(us4v*)&sBl[row] = lv;
            }
        }
    }
    __syncthreads();

    // ---- hidden layers: D = W^T(A-op) x Act(B-op), 3-product split-bf16 ----
    #pragma unroll
    for (int L = 0; L < 2; ++L) {
        const unsigned short* wshi = ws + (size_t)L * 2 * WS_ELEMS;
        const unsigned short* wslo = wshi + WS_ELEMS;

        s8v whi[2][4], wlo[2][4];   // [buf][mt] double-buffered per ks stage
        #pragma unroll
        for (int mt = 0; mt < 4; ++mt) {
            const int idx = (mh * 4 + mt) * 256 + lane;   // ks = 0
            whi[0][mt] = *(const s8v*)&wshi[(size_t)idx * 8];
            wlo[0][mt] = *(const s8v*)&wslo[(size_t)idx * 8];
        }

        v4f acc[4][NC];   // [mt][c]
        #pragma unroll
        for (int mt = 0; mt < 4; ++mt)
            #pragma unroll
            for (int c = 0; c < NC; ++c)
                acc[mt][c] = (v4f){0.0f, 0.0f, 0.0f, 0.0f};

        #pragma unroll
        for (int ks = 0; ks < 4; ++ks) {
            const int cur = ks & 1, nxt = cur ^ 1;
            if (ks < 3) {   // prefetch next stage from L2 while MFMAs run
                #pragma unroll
                for (int mt = 0; mt < 4; ++mt) {
                    const int idx = (mh * 4 + mt) * 256 + (ks + 1) * 64 + lane;
                    whi[nxt][mt] = *(const s8v*)&wshi[(size_t)idx * 8];
                    wlo[nxt][mt] = *(const s8v*)&wslo[(size_t)idx * 8];
                }
            }
            #pragma unroll
            for (int c = 0; c < NC; ++c) {
                const int rb = ((c * 2 + pt) * 16 + l15) * KP + quad * 8 + ks * 32;
                s8v bh = *(const s8v*)&sBh[rb];
                s8v bl = *(const s8v*)&sBl[rb];
                #pragma unroll
                for (int mt = 0; mt < 4; ++mt)
                    acc[mt][c] = __builtin_amdgcn_mfma_f32_16x16x32_bf16(
                        whi[cur][mt], bh, acc[mt][c], 0, 0, 0);
                #pragma unroll
                for (int mt = 0; mt < 4; ++mt)
                    acc[mt][c] = __builtin_amdgcn_mfma_f32_16x16x32_bf16(
                        whi[cur][mt], bl, acc[mt][c], 0, 0, 0);
                #pragma unroll
                for (int mt = 0; mt < 4; ++mt)
                    acc[mt][c] = __builtin_amdgcn_mfma_f32_16x16x32_bf16(
                        wlo[cur][mt], bh, acc[mt][c], 0, 0, 0);
            }
        }
        __syncthreads();            // all waves done reading sB

        const float* __restrict__ bptr = (L == 0) ? b1 : b2;
        #pragma unroll
        for (int mt = 0; mt < 4; ++mt) {
            const int jb = (mh * 4 + mt) * 16 + quad * 4;   // 4 consecutive j
            unsigned short hk[NC][4], lk[NC][4];
            #pragma unroll
            for (int r = 0; r < 4; ++r) {
                float z = acc[mt][0][r] + bptr[jb + r];
                float a = fast_tanh(z);
                float t = fmaf(-a, a, 1.0f);
                float ch[NC];
                ch[0] = a;
                if (NC == 4) {
                    float zx = acc[mt][1][r], zy = acc[mt][2][r], zl = acc[mt][3][r];
                    float s2 = fmaf(zx, zx, zy * zy);
                    ch[1] = t * zx;
                    ch[2] = t * zy;
                    ch[3] = fmaf(t, zl, -2.0f * a * t * s2);
                }
                #pragma unroll
                for (int c = 0; c < NC; ++c) {
                    unsigned short hh = f2bf(ch[c]);
                    hk[c][r] = hh;
                    lk[c][r] = f2bf(ch[c] - bf2f(hh));
                }
            }
            #pragma unroll
            for (int c = 0; c < NC; ++c) {
                if (L == 1 && c != RC) continue;    // last layer: only readout channel
                const int row = (c * 32 + pt * 16 + l15) * KP + jb;
                us4v hv = {hk[c][0], hk[c][1], hk[c][2], hk[c][3]};
                us4v lv = {lk[c][0], lk[c][1], lk[c][2], lk[c][3]};
                *(us4v*)&sBh[row] = hv;
                *(us4v*)&sBl[row] = lv;
            }
        }
        __syncthreads();
    }

    // ---- readout: dot with W3 over k, 8 lanes per point ----
    {
        const int p  = tid >> 3;
        const int i  = tid & 7;
        const int k0 = i * 16;
        const int row = (RC * 32 + p) * KP + k0;
        float r = 0.0f;
        #pragma unroll
        for (int h = 0; h < 2; ++h) {
            s8v vh = *(const s8v*)&sBh[row + h * 8];
            s8v vl = *(const s8v*)&sBl[row + h * 8];
            #pragma unroll
            for (int t = 0; t < 8; ++t) {
                float av = bf2f((unsigned short)vh[t]) + bf2f((unsigned short)vl[t]);
                r = fmaf(av, W3[k0 + h * 8 + t], r);
            }
        }
        r += __shfl_xor(r, 1, 64);
        r += __shfl_xor(r, 2, 64);
        r += __shfl_xor(r, 4, 64);
        if (i == 0) {
            float d = r + ((NC == 1) ? b3[0] : 0.0f) - tgt[pbase + p];  // lap kills b3
            sRed[p] = d * d;
        }
    }
    __syncthreads();
    if (tid == 0) {
        float s = 0.0f;
        #pragma unroll
        for (int p = 0; p < PTS; ++p) s += sRed[p];
        atomicAdd(out_slot, s * scale);
    }
}

extern "C" void kernel_launch(void* const* d_in, const int* in_sizes, int n_in,
                              void* d_out, int out_size, void* d_ws, size_t ws_size,
                              hipStream_t stream) {
    const float* xy_int = (const float*)d_in[0];
    const float* f      = (const float*)d_in[1];
    const float* xy_bd  = (const float*)d_in[2];
    const float* g      = (const float*)d_in[3];
    const float* W0 = (const float*)d_in[4];
    const float* b0 = (const float*)d_in[5];
    const float* W1 = (const float*)d_in[6];
    const float* b1 = (const float*)d_in[7];
    const float* W2 = (const float*)d_in[8];
    const float* b2 = (const float*)d_in[9];
    const float* W3 = (const float*)d_in[10];
    const float* b3 = (const float*)d_in[11];
    float* out = (float*)d_out;
    unsigned short* ws = (unsigned short*)d_ws;   // needs 256 KB

    const int n_int = in_sizes[0] / 2;   // 262144
    const int n_bd  = in_sizes[2] / 2;   // 16384

    prep_w_kernel<<<16, 256, 0, stream>>>(W1, W2, ws);
    zero_out_kernel<<<1, 64, 0, stream>>>(out);

    const int smem_int = (2 * 4 * 32 * KP) * 2 + PTS * 4;  // 69,760 B -> 2 blocks/CU
    const int smem_bd  = (2 * 1 * 32 * KP) * 2 + PTS * 4;  // 17,536 B
    const int gi = n_int / PTS;
    const int gb = n_bd / PTS;

    pinn_mfma_kernel<4><<<gi, 256, smem_int, stream>>>(
        xy_int, f, W0, b0, b1, b2, W3, b3, ws,
        out + 1, 0.5f / (float)n_int);
    pinn_mfma_kernel<1><<<gb, 256, smem_bd, stream>>>(
        xy_bd, g, W0, b0, b1, b2, W3, b3, ws,
        out + 0, 0.5f / (float)n_bd);
}

// Round 6
// 283.003 us; speedup vs baseline: 5.0065x; 1.1119x over previous
//
#include <hip/hip_runtime.h>

#define HID 128
#define PTS 32
#define KP  136   // sB k-row stride in bf16 units (128 + 8 pad)
#define FRAGS_PER_W 2048           // 8 mtg * 4 ks * 64 lanes
#define WS_ELEMS (FRAGS_PER_W * 8) // ushorts per (w, hi/lo) plane

typedef float v4f __attribute__((ext_vector_type(4)));
typedef short s8v __attribute__((ext_vector_type(8)));          // 8 bf16 (MFMA A/B frag)

__device__ __forceinline__ unsigned short f2bf(float f) {       // RNE (prep only)
    unsigned u = __builtin_bit_cast(unsigned, f);
    u = (u + 0x7FFFu + ((u >> 16) & 1u)) >> 16;
    return (unsigned short)u;
}
__device__ __forceinline__ float bf2f(unsigned short h) {
    unsigned u = ((unsigned)h) << 16;
    return __builtin_bit_cast(float, u);
}
__device__ __forceinline__ float fast_tanh(float x) {
    float e = __expf(2.0f * x);
    float r = __builtin_amdgcn_rcpf(e + 1.0f);
    return 1.0f - 2.0f * r;
}

// pack hi-16 of two fp32 into one u32: (hi16(f1)<<16)|hi16(f0)  -- 1 v_perm_b32
__device__ __forceinline__ unsigned pack_hi2(float f0, float f1) {
    return __builtin_amdgcn_perm(__builtin_bit_cast(unsigned, f1),
                                 __builtin_bit_cast(unsigned, f0), 0x07060302u);
}
__device__ __forceinline__ float trunc_resid(float f) {         // exact: low mantissa
    unsigned u = __builtin_bit_cast(unsigned, f) & 0xFFFF0000u;
    return f - __builtin_bit_cast(float, u);
}
// 4 fp32 -> trunc-split hi/lo packed pairs (6 VALU + 4 sub total)
__device__ __forceinline__ void split4(const float* f, uint2& h, uint2& l) {
    h.x = pack_hi2(f[0], f[1]);
    h.y = pack_hi2(f[2], f[3]);
    float d0 = trunc_resid(f[0]), d1 = trunc_resid(f[1]);
    float d2 = trunc_resid(f[2]), d3 = trunc_resid(f[3]);
    l.x = pack_hi2(d0, d1);
    l.y = pack_hi2(d2, d3);
}

// One-time: W1/W2 -> RNE-split bf16 A-fragments, frag-linear in d_ws; zero d_out.
// ws plane order: [W1hi][W1lo][W2hi][W2lo]; frag idx r = mtg*256 + ks*64 + lane.
__global__ __launch_bounds__(256) void prep_w_kernel(
    const float* __restrict__ W1, const float* __restrict__ W2,
    unsigned short* __restrict__ ws, float* __restrict__ out)
{
    if (blockIdx.x == 0 && threadIdx.x < 2) out[threadIdx.x] = 0.0f;
    const int t = blockIdx.x * 256 + threadIdx.x;   // 0..4095
    const int w = t >> 11;
    const int r = t & 2047;
    const int mtg = r >> 8;
    const int ks = (r >> 6) & 3;
    const int lane = r & 63;
    const int m = mtg * 16 + (lane & 15);
    const int kb = ks * 32 + (lane >> 4) * 8;
    const float* W = w ? W2 : W1;
    s8v hv, lv;
    #pragma unroll
    for (int i = 0; i < 8; ++i) {
        float f = W[(kb + i) * HID + m];            // A[m][k] = W[k][m]
        unsigned short hh = f2bf(f);
        hv[i] = (short)hh;
        lv[i] = (short)f2bf(f - bf2f(hh));
    }
    *(s8v*)&ws[((size_t)(w * 2 + 0) * FRAGS_PER_W + r) * 8] = hv;
    *(s8v*)&ws[((size_t)(w * 2 + 1) * FRAGS_PER_W + r) * 8] = lv;
}

// Fused interior+boundary. Blocks [0,gi): interior (readout=lap ch 3, no b3);
// blocks [gi, gi+gb): boundary (readout=value ch 0, +b3). All branches block-uniform.
// One block = 32 points, 4 channels (0=val,1=dx,2=dy,3=lap), split-bf16 MFMA
// (3 products ~ fp32). Wave grid: (j-half mh) x (p-half pt).
// C/D layout (m89): col=lane&15, row=quad*4+reg.
__global__ __launch_bounds__(256, 2) void pinn_mfma_kernel(
    const float* __restrict__ xy_int, const float* __restrict__ f_t,
    const float* __restrict__ xy_bd, const float* __restrict__ g_t,
    const float* __restrict__ W0, const float* __restrict__ b0,
    const float* __restrict__ b1, const float* __restrict__ b2,
    const float* __restrict__ W3, const float* __restrict__ b3,
    const unsigned short* __restrict__ ws, float* __restrict__ out,
    int gi, float scale_int, float scale_bd)
{
    extern __shared__ char smem_raw[];
    unsigned short* sBh = (unsigned short*)smem_raw;     // [4*32][KP] bf16 hi
    unsigned short* sBl = sBh + 4 * 32 * KP;             // [4*32][KP] bf16 lo
    float* sRed = (float*)(sBl + 4 * 32 * KP);           // [PTS]

    const bool is_bd = (int)blockIdx.x >= gi;
    const float* __restrict__ xy  = is_bd ? xy_bd : xy_int;
    const float* __restrict__ tgt = is_bd ? g_t : f_t;
    const int rc = is_bd ? 0 : 3;                        // readout channel
    const int pbase = (is_bd ? ((int)blockIdx.x - gi) : (int)blockIdx.x) * PTS;

    const int tid   = threadIdx.x;
    const int lane  = tid & 63;
    const int wave  = tid >> 6;
    const int l15   = lane & 15;
    const int quad  = lane >> 4;
    const int mh    = wave & 1;     // j-half: m-tiles mh*4..mh*4+3
    const int pt    = wave >> 1;    // p-half: cols pt*16..pt*16+15

    // ---- layer 0: 2 -> 128, VALU, trunc-split store into sB ----
    {
        const int tj = tid & 31, tp = tid >> 5;
        const int j0 = tj * 4, p0 = tp * 4;
        float wx[4], wy[4], bb[4];
        #pragma unroll
        for (int jj = 0; jj < 4; ++jj) {
            wx[jj] = W0[j0 + jj];
            wy[jj] = W0[HID + j0 + jj];
            bb[jj] = b0[j0 + jj];
        }
        #pragma unroll
        for (int pp = 0; pp < 4; ++pp) {
            const int p = p0 + pp;
            const float2 t2 = ((const float2*)xy)[pbase + p];
            float chv[4][4];                    // [c][jj]
            #pragma unroll
            for (int jj = 0; jj < 4; ++jj) {
                float z = fmaf(t2.x, wx[jj], fmaf(t2.y, wy[jj], bb[jj]));
                float a = fast_tanh(z);
                float t = fmaf(-a, a, 1.0f);
                float s2 = fmaf(wx[jj], wx[jj], wy[jj] * wy[jj]);
                chv[0][jj] = a;
                chv[1][jj] = t * wx[jj];
                chv[2][jj] = t * wy[jj];
                chv[3][jj] = -2.0f * a * t * s2;        // z_lap = 0 at layer 0
            }
            #pragma unroll
            for (int c = 0; c < 4; ++c) {
                const int row = (c * 32 + p) * KP + j0; // multiple of 4 -> 8B aligned
                uint2 hv, lv;
                split4(chv[c], hv, lv);
                *(uint2*)&sBh[row] = hv;
                *(uint2*)&sBl[row] = lv;
            }
        }
    }
    __syncthreads();

    // ---- hidden layers: D = W^T(A-op) x Act(B-op), 3-product split-bf16 ----
    #pragma unroll
    for (int L = 0; L < 2; ++L) {
        const unsigned short* wshi = ws + (size_t)L * 2 * WS_ELEMS;
        const unsigned short* wslo = wshi + WS_ELEMS;

        s8v whi[2][4], wlo[2][4];   // [buf][mt] double-buffered per ks stage
        #pragma unroll
        for (int mt = 0; mt < 4; ++mt) {
            const int idx = (mh * 4 + mt) * 256 + lane;   // ks = 0
            whi[0][mt] = *(const s8v*)&wshi[(size_t)idx * 8];
            wlo[0][mt] = *(const s8v*)&wslo[(size_t)idx * 8];
        }

        v4f acc[4][4];   // [mt][c]
        #pragma unroll
        for (int mt = 0; mt < 4; ++mt)
            #pragma unroll
            for (int c = 0; c < 4; ++c)
                acc[mt][c] = (v4f){0.0f, 0.0f, 0.0f, 0.0f};

        #pragma unroll
        for (int ks = 0; ks < 4; ++ks) {
            const int cur = ks & 1, nxt = cur ^ 1;
            if (ks < 3) {   // prefetch next stage from L2 while MFMAs run
                #pragma unroll
                for (int mt = 0; mt < 4; ++mt) {
                    const int idx = (mh * 4 + mt) * 256 + (ks + 1) * 64 + lane;
                    whi[nxt][mt] = *(const s8v*)&wshi[(size_t)idx * 8];
                    wlo[nxt][mt] = *(const s8v*)&wslo[(size_t)idx * 8];
                }
            }
            #pragma unroll
            for (int c = 0; c < 4; ++c) {
                const int rb = ((c * 2 + pt) * 16 + l15) * KP + quad * 8 + ks * 32;
                s8v bh = *(const s8v*)&sBh[rb];
                s8v bl = *(const s8v*)&sBl[rb];
                #pragma unroll
                for (int mt = 0; mt < 4; ++mt)
                    acc[mt][c] = __builtin_amdgcn_mfma_f32_16x16x32_bf16(
                        whi[cur][mt], bh, acc[mt][c], 0, 0, 0);
                #pragma unroll
                for (int mt = 0; mt < 4; ++mt)
                    acc[mt][c] = __builtin_amdgcn_mfma_f32_16x16x32_bf16(
                        whi[cur][mt], bl, acc[mt][c], 0, 0, 0);
                #pragma unroll
                for (int mt = 0; mt < 4; ++mt)
                    acc[mt][c] = __builtin_amdgcn_mfma_f32_16x16x32_bf16(
                        wlo[cur][mt], bh, acc[mt][c], 0, 0, 0);
            }
        }
        __syncthreads();            // all waves done reading sB

        const float* __restrict__ bptr = (L == 0) ? b1 : b2;
        #pragma unroll
        for (int mt = 0; mt < 4; ++mt) {
            const int jb = (mh * 4 + mt) * 16 + quad * 4;   // 4 consecutive j
            float chv[4][4];                                // [c][r]
            #pragma unroll
            for (int r = 0; r < 4; ++r) {
                float z = acc[mt][0][r] + bptr[jb + r];
                float a = fast_tanh(z);
                float t = fmaf(-a, a, 1.0f);
                float zx = acc[mt][1][r], zy = acc[mt][2][r], zl = acc[mt][3][r];
                float s2 = fmaf(zx, zx, zy * zy);
                chv[0][r] = a;
                chv[1][r] = t * zx;
                chv[2][r] = t * zy;
                chv[3][r] = fmaf(t, zl, -2.0f * a * t * s2);
            }
            #pragma unroll
            for (int c = 0; c < 4; ++c) {
                if (L == 1 && c != rc) continue;    // uniform branch: skip dead conv+store
                const int row = (c * 32 + pt * 16 + l15) * KP + jb;
                uint2 hv, lv;
                split4(chv[c], hv, lv);
                *(uint2*)&sBh[row] = hv;
                *(uint2*)&sBl[row] = lv;
            }
        }
        __syncthreads();
    }

    // ---- readout: dot with W3 over k, 8 lanes per point ----
    {
        const int p  = tid >> 3;
        const int i  = tid & 7;
        const int k0 = i * 16;
        const int row = (rc * 32 + p) * KP + k0;
        float r = 0.0f;
        #pragma unroll
        for (int h = 0; h < 2; ++h) {
            s8v vh = *(const s8v*)&sBh[row + h * 8];
            s8v vl = *(const s8v*)&sBl[row + h * 8];
            #pragma unroll
            for (int t = 0; t < 8; ++t) {
                float av = bf2f((unsigned short)vh[t]) + bf2f((unsigned short)vl[t]);
                r = fmaf(av, W3[k0 + h * 8 + t], r);
            }
        }
        r += __shfl_xor(r, 1, 64);
        r += __shfl_xor(r, 2, 64);
        r += __shfl_xor(r, 4, 64);
        if (i == 0) {
            float d = r + (is_bd ? b3[0] : 0.0f) - tgt[pbase + p];  // lap kills b3
            sRed[p] = d * d;
        }
    }
    __syncthreads();
    if (tid == 0) {
        float s = 0.0f;
        #pragma unroll
        for (int p = 0; p < PTS; ++p) s += sRed[p];
        atomicAdd(out + (is_bd ? 0 : 1), s * (is_bd ? scale_bd : scale_int));
    }
}

extern "C" void kernel_launch(void* const* d_in, const int* in_sizes, int n_in,
                              void* d_out, int out_size, void* d_ws, size_t ws_size,
                              hipStream_t stream) {
    const float* xy_int = (const float*)d_in[0];
    const float* f      = (const float*)d_in[1];
    const float* xy_bd  = (const float*)d_in[2];
    const float* g      = (const float*)d_in[3];
    const float* W0 = (const float*)d_in[4];
    const float* b0 = (const float*)d_in[5];
    const float* W1 = (const float*)d_in[6];
    const float* b1 = (const float*)d_in[7];
    const float* W2 = (const float*)d_in[8];
    const float* b2 = (const float*)d_in[9];
    const float* W3 = (const float*)d_in[10];
    const float* b3 = (const float*)d_in[11];
    float* out = (float*)d_out;
    unsigned short* ws = (unsigned short*)d_ws;   // needs 256 KB

    const int n_int = in_sizes[0] / 2;   // 262144
    const int n_bd  = in_sizes[2] / 2;   // 16384

    prep_w_kernel<<<16, 256, 0, stream>>>(W1, W2, ws, out);

    const int smem = (2 * 4 * 32 * KP) * 2 + PTS * 4;  // 69,760 B -> 2 blocks/CU
    const int gi = n_int / PTS;
    const int gb = n_bd / PTS;

    pinn_mfma_kernel<<<gi + gb, 256, smem, stream>>>(
        xy_int, f, xy_bd, g, W0, b0, b1, b2, W3, b3, ws, out,
        gi, 0.5f / (float)n_int, 0.5f / (float)n_bd);
}

// Round 7
// 230.000 us; speedup vs baseline: 6.1602x; 1.2304x over previous
//
#include <hip/hip_runtime.h>

#define HID 128
#define PTS 32
#define KP  136   // sB k-row stride in bf16 units (128 + 8 pad)
#define FRAGS_PER_W 2048           // 8 mtg * 4 ks * 64 lanes
#define WS_ELEMS (FRAGS_PER_W * 8) // ushorts per (w, hi/lo) plane

typedef float v4f __attribute__((ext_vector_type(4)));
typedef short s8v __attribute__((ext_vector_type(8)));          // 8 bf16 (MFMA A/B frag)

__device__ __forceinline__ unsigned short f2bf(float f) {       // RNE (prep only)
    unsigned u = __builtin_bit_cast(unsigned, f);
    u = (u + 0x7FFFu + ((u >> 16) & 1u)) >> 16;
    return (unsigned short)u;
}
__device__ __forceinline__ float bf2f(unsigned short h) {
    unsigned u = ((unsigned)h) << 16;
    return __builtin_bit_cast(float, u);
}
__device__ __forceinline__ float fast_tanh(float x) {
    float e = __expf(2.0f * x);
    float r = __builtin_amdgcn_rcpf(e + 1.0f);
    return 1.0f - 2.0f * r;
}

// RNE-round two fp32 to bf16 and pack: (bf(f1)<<16)|bf(f0).  ~3 VALU/elem + 1 perm
__device__ __forceinline__ unsigned rne_pack2(float f0, float f1) {
    unsigned u0 = __builtin_bit_cast(unsigned, f0);
    unsigned u1 = __builtin_bit_cast(unsigned, f1);
    u0 += 0x7FFFu + ((u0 >> 16) & 1u);
    u1 += 0x7FFFu + ((u1 >> 16) & 1u);
    // out bytes (LE): {u0.b2, u0.b3, u1.b2, u1.b3} -> perm(src0=u1, src1=u0)
    return __builtin_amdgcn_perm(u1, u0, 0x07060302u);
}
// 4 fp32 -> packed RNE bf16 x4
__device__ __forceinline__ uint2 rne4(const float* f) {
    uint2 h;
    h.x = rne_pack2(f[0], f[1]);
    h.y = rne_pack2(f[2], f[3]);
    return h;
}

// One-time: W1/W2 -> RNE-split bf16 A-fragments, frag-linear in d_ws; zero d_out.
// ws plane order: [W1hi][W1lo][W2hi][W2lo]; frag idx r = mtg*256 + ks*64 + lane.
__global__ __launch_bounds__(256) void prep_w_kernel(
    const float* __restrict__ W1, const float* __restrict__ W2,
    unsigned short* __restrict__ ws, float* __restrict__ out)
{
    if (blockIdx.x == 0 && threadIdx.x < 2) out[threadIdx.x] = 0.0f;
    const int t = blockIdx.x * 256 + threadIdx.x;   // 0..4095
    const int w = t >> 11;
    const int r = t & 2047;
    const int mtg = r >> 8;
    const int ks = (r >> 6) & 3;
    const int lane = r & 63;
    const int m = mtg * 16 + (lane & 15);
    const int kb = ks * 32 + (lane >> 4) * 8;
    const float* W = w ? W2 : W1;
    s8v hv, lv;
    #pragma unroll
    for (int i = 0; i < 8; ++i) {
        float f = W[(kb + i) * HID + m];            // A[m][k] = W[k][m]
        unsigned short hh = f2bf(f);
        hv[i] = (short)hh;
        lv[i] = (short)f2bf(f - bf2f(hh));
    }
    *(s8v*)&ws[((size_t)(w * 2 + 0) * FRAGS_PER_W + r) * 8] = hv;
    *(s8v*)&ws[((size_t)(w * 2 + 1) * FRAGS_PER_W + r) * 8] = lv;
}

// Fused interior+boundary. Blocks [0,gi): interior (readout=lap ch 3, no b3);
// blocks [gi, gi+gb): boundary (readout=value ch 0, +b3). All branches block-uniform.
// One block = 32 points, 4 channels (0=val,1=dx,2=dy,3=lap).
// 2-product split-bf16 MFMA: W = whi + wlo (exact to 2^-18, registers),
// activations single RNE bf16 in LDS (error zero-mean -> averages out in loss).
// Wave grid: (j-half mh) x (p-half pt). C/D layout (m89): col=lane&15, row=quad*4+reg.
// LDS 34.9 KB -> 4 blocks/CU: phases overlap across blocks (m114).
__global__ __launch_bounds__(256, 4) void pinn_mfma_kernel(
    const float* __restrict__ xy_int, const float* __restrict__ f_t,
    const float* __restrict__ xy_bd, const float* __restrict__ g_t,
    const float* __restrict__ W0, const float* __restrict__ b0,
    const float* __restrict__ b1, const float* __restrict__ b2,
    const float* __restrict__ W3, const float* __restrict__ b3,
    const unsigned short* __restrict__ ws, float* __restrict__ out,
    int gi, float scale_int, float scale_bd)
{
    extern __shared__ char smem_raw[];
    unsigned short* sBh = (unsigned short*)smem_raw;     // [4*32][KP] bf16 (RNE)
    float* sRed = (float*)(sBh + 4 * 32 * KP);           // [PTS]

    const bool is_bd = (int)blockIdx.x >= gi;
    const float* __restrict__ xy  = is_bd ? xy_bd : xy_int;
    const float* __restrict__ tgt = is_bd ? g_t : f_t;
    const int rc = is_bd ? 0 : 3;                        // readout channel
    const int pbase = (is_bd ? ((int)blockIdx.x - gi) : (int)blockIdx.x) * PTS;

    const int tid   = threadIdx.x;
    const int lane  = tid & 63;
    const int wave  = tid >> 6;
    const int l15   = lane & 15;
    const int quad  = lane >> 4;
    const int mh    = wave & 1;     // j-half: m-tiles mh*4..mh*4+3
    const int pt    = wave >> 1;    // p-half: cols pt*16..pt*16+15

    // ---- layer 0: 2 -> 128, VALU, RNE-bf16 store into sB ----
    {
        const int tj = tid & 31, tp = tid >> 5;
        const int j0 = tj * 4, p0 = tp * 4;
        float wx[4], wy[4], bb[4];
        #pragma unroll
        for (int jj = 0; jj < 4; ++jj) {
            wx[jj] = W0[j0 + jj];
            wy[jj] = W0[HID + j0 + jj];
            bb[jj] = b0[j0 + jj];
        }
        #pragma unroll
        for (int pp = 0; pp < 4; ++pp) {
            const int p = p0 + pp;
            const float2 t2 = ((const float2*)xy)[pbase + p];
            float chv[4][4];                    // [c][jj]
            #pragma unroll
            for (int jj = 0; jj < 4; ++jj) {
                float z = fmaf(t2.x, wx[jj], fmaf(t2.y, wy[jj], bb[jj]));
                float a = fast_tanh(z);
                float t = fmaf(-a, a, 1.0f);
                float s2 = fmaf(wx[jj], wx[jj], wy[jj] * wy[jj]);
                chv[0][jj] = a;
                chv[1][jj] = t * wx[jj];
                chv[2][jj] = t * wy[jj];
                chv[3][jj] = -2.0f * a * t * s2;        // z_lap = 0 at layer 0
            }
            #pragma unroll
            for (int c = 0; c < 4; ++c) {
                const int row = (c * 32 + p) * KP + j0; // j0 mult of 4 -> 8B aligned
                *(uint2*)&sBh[row] = rne4(chv[c]);
            }
        }
    }
    __syncthreads();

    // ---- hidden layers: D = (Whi + Wlo)(A-op) x Act(B-op), 2-product ----
    #pragma unroll
    for (int L = 0; L < 2; ++L) {
        const unsigned short* wshi = ws + (size_t)L * 2 * WS_ELEMS;
        const unsigned short* wslo = wshi + WS_ELEMS;

        s8v whi[2][4], wlo[2][4];   // [buf][mt] double-buffered per ks stage
        #pragma unroll
        for (int mt = 0; mt < 4; ++mt) {
            const int idx = (mh * 4 + mt) * 256 + lane;   // ks = 0
            whi[0][mt] = *(const s8v*)&wshi[(size_t)idx * 8];
            wlo[0][mt] = *(const s8v*)&wslo[(size_t)idx * 8];
        }

        v4f acc[4][4];   // [mt][c]
        #pragma unroll
        for (int mt = 0; mt < 4; ++mt)
            #pragma unroll
            for (int c = 0; c < 4; ++c)
                acc[mt][c] = (v4f){0.0f, 0.0f, 0.0f, 0.0f};

        #pragma unroll
        for (int ks = 0; ks < 4; ++ks) {
            const int cur = ks & 1, nxt = cur ^ 1;
            if (ks < 3) {   // prefetch next stage from L2 while MFMAs run
                #pragma unroll
                for (int mt = 0; mt < 4; ++mt) {
                    const int idx = (mh * 4 + mt) * 256 + (ks + 1) * 64 + lane;
                    whi[nxt][mt] = *(const s8v*)&wshi[(size_t)idx * 8];
                    wlo[nxt][mt] = *(const s8v*)&wslo[(size_t)idx * 8];
                }
            }
            #pragma unroll
            for (int c = 0; c < 4; ++c) {
                const int rb = ((c * 2 + pt) * 16 + l15) * KP + quad * 8 + ks * 32;
                s8v bh = *(const s8v*)&sBh[rb];
                #pragma unroll
                for (int mt = 0; mt < 4; ++mt)
                    acc[mt][c] = __builtin_amdgcn_mfma_f32_16x16x32_bf16(
                        whi[cur][mt], bh, acc[mt][c], 0, 0, 0);
                #pragma unroll
                for (int mt = 0; mt < 4; ++mt)
                    acc[mt][c] = __builtin_amdgcn_mfma_f32_16x16x32_bf16(
                        wlo[cur][mt], bh, acc[mt][c], 0, 0, 0);
            }
        }
        __syncthreads();            // all waves done reading sB

        const float* __restrict__ bptr = (L == 0) ? b1 : b2;
        #pragma unroll
        for (int mt = 0; mt < 4; ++mt) {
            const int jb = (mh * 4 + mt) * 16 + quad * 4;   // 4 consecutive j
            float chv[4][4];                                // [c][r]
            #pragma unroll
            for (int r = 0; r < 4; ++r) {
                float z = acc[mt][0][r] + bptr[jb + r];
                float a = fast_tanh(z);
                float t = fmaf(-a, a, 1.0f);
                float zx = acc[mt][1][r], zy = acc[mt][2][r], zl = acc[mt][3][r];
                float s2 = fmaf(zx, zx, zy * zy);
                chv[0][r] = a;
                chv[1][r] = t * zx;
                chv[2][r] = t * zy;
                chv[3][r] = fmaf(t, zl, -2.0f * a * t * s2);
            }
            #pragma unroll
            for (int c = 0; c < 4; ++c) {
                if (L == 1 && c != rc) continue;    // uniform: skip dead conv+store
                const int row = (c * 32 + pt * 16 + l15) * KP + jb;
                *(uint2*)&sBh[row] = rne4(chv[c]);
            }
        }
        __syncthreads();
    }

    // ---- readout: dot with W3 over k, 8 lanes per point ----
    {
        const int p  = tid >> 3;
        const int i  = tid & 7;
        const int k0 = i * 16;
        const int row = (rc * 32 + p) * KP + k0;
        float r = 0.0f;
        #pragma unroll
        for (int h = 0; h < 2; ++h) {
            s8v vh = *(const s8v*)&sBh[row + h * 8];
            #pragma unroll
            for (int t = 0; t < 8; ++t)
                r = fmaf(bf2f((unsigned short)vh[t]), W3[k0 + h * 8 + t], r);
        }
        r += __shfl_xor(r, 1, 64);
        r += __shfl_xor(r, 2, 64);
        r += __shfl_xor(r, 4, 64);
        if (i == 0) {
            float d = r + (is_bd ? b3[0] : 0.0f) - tgt[pbase + p];  // lap kills b3
            sRed[p] = d * d;
        }
    }
    __syncthreads();
    if (tid == 0) {
        float s = 0.0f;
        #pragma unroll
        for (int p = 0; p < PTS; ++p) s += sRed[p];
        atomicAdd(out + (is_bd ? 0 : 1), s * (is_bd ? scale_bd : scale_int));
    }
}

extern "C" void kernel_launch(void* const* d_in, const int* in_sizes, int n_in,
                              void* d_out, int out_size, void* d_ws, size_t ws_size,
                              hipStream_t stream) {
    const float* xy_int = (const float*)d_in[0];
    const float* f      = (const float*)d_in[1];
    const float* xy_bd  = (const float*)d_in[2];
    const float* g      = (const float*)d_in[3];
    const float* W0 = (const float*)d_in[4];
    const float* b0 = (const float*)d_in[5];
    const float* W1 = (const float*)d_in[6];
    const float* b1 = (const float*)d_in[7];
    const float* W2 = (const float*)d_in[8];
    const float* b2 = (const float*)d_in[9];
    const float* W3 = (const float*)d_in[10];
    const float* b3 = (const float*)d_in[11];
    float* out = (float*)d_out;
    unsigned short* ws = (unsigned short*)d_ws;   // needs 256 KB

    const int n_int = in_sizes[0] / 2;   // 262144
    const int n_bd  = in_sizes[2] / 2;   // 16384

    prep_w_kernel<<<16, 256, 0, stream>>>(W1, W2, ws, out);

    const int smem = (4 * 32 * KP) * 2 + PTS * 4;  // 34,944 B -> 4 blocks/CU
    const int gi = n_int / PTS;
    const int gb = n_bd / PTS;

    pinn_mfma_kernel<<<gi + gb, 256, smem, stream>>>(
        xy_int, f, xy_bd, g, W0, b0, b1, b2, W3, b3, ws, out,
        gi, 0.5f / (float)n_int, 0.5f / (float)n_bd);
}